// Round 1
// baseline (607.123 us; speedup 1.0000x reference)
//
#include <hip/hip_runtime.h>
#include <cstdint>
#include <cstddef>

// ---------------------------------------------------------------------------
// CircularSplineLayer: xn = norm(x_passive); h = tanh(xn@w1+b1);
// net = tanh(h@w2+b2) -> per (b,s) 24-vector -> softmax/softplus spline ->
// phi_out (mod 2pi), log_density -= sum_s log(grad).
//
// Pipeline:
//  k_stats          global sum/sumsq of x_passive
//  k_prep           xn -> bf16 [1024][4096]
//  k_transpose_cvt  w1 -> bf16 [512][4096] (n-major), w2 -> bf16 [98304][512]
//  k_gemm1          MFMA bf16 16x16x32, tile 64x64 -> h bf16 [1024][512]
//  k_gemm2          MFMA tile 256x96 (4 s_out groups), fused spline epilogue
//  k_ldred          per-b reduction of log-grad partials
// ---------------------------------------------------------------------------

typedef unsigned short u16;
typedef __bf16 bf16x8 __attribute__((ext_vector_type(8)));
typedef float f32x4 __attribute__((ext_vector_type(4)));
typedef unsigned short u16x8 __attribute__((ext_vector_type(8)));

#define TWOPI_F 6.28318530717958647692f

static __device__ __forceinline__ u16 f32_to_bf16(float f){
  unsigned u = __builtin_bit_cast(unsigned, f);
  return (u16)((u + 0x7fffu + ((u >> 16) & 1u)) >> 16);   // RNE
}
static __device__ __forceinline__ void async16(void* lds, const void* g){
  // global->LDS DMA, 16B/lane; LDS dest = wave-uniform base + lane*16
  __builtin_amdgcn_global_load_lds((const __attribute__((address_space(1))) void*)g,
                                   (__attribute__((address_space(3))) void*)lds,
                                   16, 0, 0);
}
static __device__ __forceinline__ float fast_tanh(float x){
  x = fminf(fmaxf(x, -15.f), 15.f);
  float e = __expf(2.f * x);
  return (e - 1.f) / (e + 1.f);
}
static __device__ __forceinline__ float softplus_f(float x){
  return fmaxf(x, 0.f) + __logf(1.f + __expf(-fabsf(x)));
}

// ---- global sum / sumsq of x_passive (4194304 f32) ----
__global__ void k_stats(const float* __restrict__ xp, float* __restrict__ stats){
  __shared__ float ss[4], sq[4];
  const int tid = threadIdx.x;
  const long gt = (long)blockIdx.x * 256 + tid;          // float4 index
  const float4* x4 = (const float4*)xp;
  float s = 0.f, q = 0.f;
  #pragma unroll
  for (int p = 0; p < 4; ++p){
    float4 v = x4[gt + (long)p * 262144];
    s += v.x + v.y + v.z + v.w;
    q += v.x*v.x + v.y*v.y + v.z*v.z + v.w*v.w;
  }
  #pragma unroll
  for (int off = 32; off; off >>= 1){
    s += __shfl_down(s, off);
    q += __shfl_down(q, off);
  }
  if ((tid & 63) == 0){ ss[tid>>6] = s; sq[tid>>6] = q; }
  __syncthreads();
  if (tid == 0){
    atomicAdd(stats,     ss[0]+ss[1]+ss[2]+ss[3]);
    atomicAdd(stats + 1, sq[0]+sq[1]+sq[2]+sq[3]);
  }
}

// ---- xn = (x - mean)*istd -> bf16 ----
__global__ void k_prep(const float* __restrict__ xp, const float* __restrict__ stats,
                       u16* __restrict__ xn){
  const long t = (long)blockIdx.x * 256 + threadIdx.x;   // 524288 threads, 8 elems each
  const float sum = stats[0], sq = stats[1];
  const float N = 4194304.f;
  const float mean = sum / N;
  const float istd = rsqrtf((sq - sum*sum/N) / (N - 1.f));  // ddof=1
  const float4* x4 = (const float4*)xp;
  const float4 a = x4[2*t], b = x4[2*t+1];
  u16x8 o;
  o[0]=f32_to_bf16((a.x-mean)*istd); o[1]=f32_to_bf16((a.y-mean)*istd);
  o[2]=f32_to_bf16((a.z-mean)*istd); o[3]=f32_to_bf16((a.w-mean)*istd);
  o[4]=f32_to_bf16((b.x-mean)*istd); o[5]=f32_to_bf16((b.y-mean)*istd);
  o[6]=f32_to_bf16((b.z-mean)*istd); o[7]=f32_to_bf16((b.w-mean)*istd);
  ((u16x8*)xn)[t] = o;
}

// ---- f32 [Kd][Nd] -> bf16 [Nd][Kd] (64x64 tiles via LDS) ----
__global__ void k_transpose_cvt(const float* __restrict__ in, u16* __restrict__ out,
                                int Kd, int Nd){
  __shared__ float tile[64][65];
  const int tid = threadIdx.x;
  const long k0 = (long)blockIdx.x * 64, n0 = (long)blockIdx.y * 64;
  const int cl = (tid & 15) * 4, rw = tid >> 4;           // rw 0..15
  #pragma unroll
  for (int p = 0; p < 4; ++p){
    const int kk = rw + p*16;
    const float4 v = *(const float4*)&in[(k0+kk)*Nd + n0 + cl];
    tile[kk][cl] = v.x; tile[kk][cl+1] = v.y; tile[kk][cl+2] = v.z; tile[kk][cl+3] = v.w;
  }
  __syncthreads();
  const int nl = tid >> 2, kc = (tid & 3) * 16;
  u16x8 o0, o1;
  #pragma unroll
  for (int i = 0; i < 8; ++i) o0[i] = f32_to_bf16(tile[kc+i][nl]);
  #pragma unroll
  for (int i = 0; i < 8; ++i) o1[i] = f32_to_bf16(tile[kc+8+i][nl]);
  u16* op = out + (n0+nl)*Kd + k0 + kc;
  *(u16x8*)op = o0;
  *(u16x8*)(op + 8) = o1;
}

// ---- GEMM1: h = tanh(xn @ w1 + b1), M=1024 N=512 K=4096, tile 64x64 ----
__global__ __launch_bounds__(256, 2) void k_gemm1(
    const u16* __restrict__ xn,   // [1024][4096] bf16
    const u16* __restrict__ w1t,  // [512][4096] bf16 (n-major)
    const float* __restrict__ b1,
    u16* __restrict__ hb)         // [1024][512] bf16
{
  __shared__ __align__(16) u16 sA[64*32];
  __shared__ __align__(16) u16 sB[64*32];
  const int tid = threadIdx.x, lane = tid & 63, w = tid >> 6;
  const int n0 = blockIdx.x << 6, m0 = blockIdx.y << 6;
  const int wm = w >> 1, wn = w & 1;
  const int rA = lane >> 2, cA = (lane & 3) << 3;
  const int fr = lane & 15, fq = lane >> 4;
  const f32x4 z4 = {0.f, 0.f, 0.f, 0.f};
  f32x4 acc[2][2];
  #pragma unroll
  for (int i=0;i<2;i++){ acc[i][0] = z4; acc[i][1] = z4; }

  for (int kt = 0; kt < 128; ++kt){
    const int kofs = (kt << 5) + cA;
    async16(sA + w*512, xn  + (long)(m0 + w*16 + rA)*4096 + kofs);
    async16(sB + w*512, w1t + (long)(n0 + w*16 + rA)*4096 + kofs);
    __syncthreads();
    bf16x8 af[2], bfv[2];
    #pragma unroll
    for (int i=0;i<2;i++) af[i]  = *(const bf16x8*)(sA + ((wm<<5) + i*16 + fr)*32 + (fq<<3));
    #pragma unroll
    for (int j=0;j<2;j++) bfv[j] = *(const bf16x8*)(sB + ((wn<<5) + j*16 + fr)*32 + (fq<<3));
    #pragma unroll
    for (int i=0;i<2;i++)
      #pragma unroll
      for (int j=0;j<2;j++)
        acc[i][j] = __builtin_amdgcn_mfma_f32_16x16x32_bf16(af[i], bfv[j], acc[i][j], 0, 0, 0);
    __syncthreads();
  }
  float b1c[2];
  #pragma unroll
  for (int j=0;j<2;j++) b1c[j] = b1[n0 + (wn<<5) + j*16 + fr];
  #pragma unroll
  for (int i=0;i<2;i++)
    #pragma unroll
    for (int j=0;j<2;j++)
      #pragma unroll
      for (int r=0;r<4;r++){
        const int row = m0 + (wm<<5) + i*16 + (fq<<2) + r;   // C/D: row=(lane>>4)*4+reg
        const int col = n0 + (wn<<5) + j*16 + fr;            //      col=lane&15
        hb[row*512 + col] = f32_to_bf16(fast_tanh(acc[i][j][r] + b1c[j]));
      }
}

// ---- GEMM2 + spline epilogue: M=1024 N=98304 K=512, tile 256x96 ----
// 4 waves stacked along M (each 64 rows x 96 cols = 4x6 16x16 frags).
// 96 cols = 4 complete s_out groups of 24 (3K).
__global__ __launch_bounds__(256, 2) void k_gemm2(
    const u16* __restrict__ hmat,   // [1024][512] bf16
    const u16* __restrict__ w2t,    // [98304][512] bf16 (n-major)
    const float* __restrict__ b2,
    const float* __restrict__ x_in, // [1024][4096]
    const float* __restrict__ phase,
    float* __restrict__ phi_out,    // [1024][4096]
    float* __restrict__ part)       // [1024][1024] log-grad partials (b, ntile)
{
  __shared__ __align__(16) char smem[25600];
  u16* sA = (u16*)smem;              // [256][32] bf16 staging
  u16* sB = (u16*)(smem + 16384);    // [128][32] bf16 (rows >=96 are pad)
  float* sC = (float*)smem;          // [4 waves][16 rows][100] epilogue (reuses smem)

  const int tid  = threadIdx.x;
  const int lane = tid & 63;
  const int w    = tid >> 6;
  const int nt   = blockIdx.x;           // 0..1023
  const int m0   = blockIdx.y << 8;      // 0,256,512,768
  const long n0  = (long)nt * 96;

  const int rA = lane >> 2, cA = (lane & 3) << 3;
  const int fr = lane & 15, fq = lane >> 4;

  const f32x4 z4 = {0.f, 0.f, 0.f, 0.f};
  f32x4 acc[4][6];
  #pragma unroll
  for (int i=0;i<4;i++)
    #pragma unroll
    for (int j=0;j<6;j++) acc[i][j] = z4;

  for (int kt = 0; kt < 16; ++kt){
    const int kofs = (kt << 5) + cA;
    #pragma unroll
    for (int cc = 0; cc < 4; ++cc){
      const int c = (w << 2) + cc;                         // 16 A chunks of 16 rows
      async16(sA + c*512, hmat + (long)(m0 + c*16 + rA)*512 + kofs);
    }
    #pragma unroll
    for (int cc = 0; cc < 2; ++cc){
      const int ch = (w << 1) + cc;                        // 8 B chunks (2 pad)
      int row = ch*16 + rA; if (row > 95) row = 95;        // clamp into valid rows
      async16(sB + ch*512, w2t + (n0 + row)*512 + kofs);
    }
    __syncthreads();                                       // drains vmcnt for DMA
    bf16x8 af[4], bfv[6];
    #pragma unroll
    for (int i=0;i<4;i++)
      af[i] = *(const bf16x8*)(sA + ((w<<6) + i*16 + fr)*32 + (fq<<3));
    #pragma unroll
    for (int j=0;j<6;j++)
      bfv[j] = *(const bf16x8*)(sB + (j*16 + fr)*32 + (fq<<3));
    #pragma unroll
    for (int i=0;i<4;i++)
      #pragma unroll
      for (int j=0;j<6;j++)
        acc[i][j] = __builtin_amdgcn_mfma_f32_16x16x32_bf16(af[i], bfv[j], acc[i][j], 0, 0, 0);
    __syncthreads();
  }

  // ---- epilogue: tanh+bias -> LDS -> per-(b,s_out) spline ----
  const float shift = phase[0];
  float b2c[6];
  #pragma unroll
  for (int j=0;j<6;j++) b2c[j] = b2[n0 + j*16 + fr];
  float* myC = sC + w*1600;                                // 16 rows x 100 floats

  #pragma unroll
  for (int q = 0; q < 4; ++q){                             // quarter = row-frag index
    __syncthreads();
    #pragma unroll
    for (int j=0;j<6;j++)
      #pragma unroll
      for (int r=0;r<4;r++)
        myC[((fq<<2)+r)*100 + j*16 + fr] = fast_tanh(acc[q][j][r] + b2c[j]);
    __syncthreads();

    const int row = fr;                 // 0..15 within quarter
    const int g   = fq;                 // s_out group 0..3
    const float* tp = myC + row*100 + g*24;
    float t[24];
    #pragma unroll
    for (int jj=0;jj<24;jj++) t[jj] = tp[jj];

    const int bg = m0 + (w<<6) + (q<<4) + row;
    const int s  = (nt<<2) + g;
    const float x = x_in[(long)bg*4096 + s];

    // softmax over h_raw (t[0..7]) and w_raw (t[8..15]); tanh out in (-1,1) so no max-shift needed
    float eh[8], ew[8];
    float sh = 0.f, sw = 0.f;
    #pragma unroll
    for (int i=0;i<8;i++){ eh[i] = __expf(t[i]);   sh += eh[i]; }
    #pragma unroll
    for (int i=0;i<8;i++){ ew[i] = __expf(t[8+i]); sw += ew[i]; }
    const float fh = TWOPI_F / sh, fw = TWOPI_F / sw;

    // bin index: #{cumsum_w_i < x, i=1..8}, clipped to 7
    float cw = 0.f; int k = 0;
    #pragma unroll
    for (int i=0;i<8;i++){ cw += ew[i]*fw; k += (cw < x) ? 1 : 0; }
    if (k > 7) k = 7;

    float xkm1 = -1e-6f, ph = 0.f, wk = 0.f, hk = 0.f, dr0 = 0.f, dr1 = 0.f;
    float cw2 = 0.f, chs = 0.f;
    #pragma unroll
    for (int i=0;i<8;i++){
      const float wi = ew[i]*fw, hi = eh[i]*fh;
      if (i == k){
        wk = wi; hk = hi;
        xkm1 = (i == 0) ? -1e-6f : cw2;   // x_kp[k]
        ph = chs;                         // phi_kp[k]
        dr0 = t[16 + i];
        dr1 = t[16 + ((i+1)&7)];
      }
      cw2 += wi; chs += hi;
    }
    const float dk  = softplus_f(dr0);
    const float dk1 = softplus_f(dr1);
    const float sk  = hk / wk;
    const float alpha = (x - xkm1) / wk;
    const float a1m = alpha * (1.f - alpha);
    const float denom = sk + (dk1 + dk - 2.f*sk)*a1m;
    const float phiv = ph + hk*(sk*alpha*alpha + dk*a1m)/denom;
    float p = phiv + shift;                 // in [0, 2pi+1): conditional subtract == mod
    if (p >= TWOPI_F) p -= TWOPI_F;
    if (p >= TWOPI_F) p -= TWOPI_F;
    phi_out[(long)bg*4096 + s] = p;

    const float om = 1.f - alpha;
    const float num = dk1*alpha*alpha + 2.f*sk*a1m + dk*om*om;
    float lg = __logf(sk*sk*num/(denom*denom));
    lg += __shfl_xor(lg, 16);               // sum over the 4 s_out groups (same row)
    lg += __shfl_xor(lg, 32);
    if (lane < 16) part[(long)bg*1024 + nt] = lg;
  }
}

// ---- log_density[b] = ldin[b] - sum_nt part[b][nt] ----
__global__ void k_ldred(const float* __restrict__ part, const float* __restrict__ ldin,
                        float* __restrict__ ldout){
  __shared__ float ss[4];
  const int b = blockIdx.x, tid = threadIdx.x;
  const float4* p4 = (const float4*)(part + ((long)b << 10));
  const float4 v = p4[tid];
  float s = v.x + v.y + v.z + v.w;
  #pragma unroll
  for (int off = 32; off; off >>= 1) s += __shfl_down(s, off);
  if ((tid & 63) == 0) ss[tid >> 6] = s;
  __syncthreads();
  if (tid == 0) ldout[b] = ldin[b] - (ss[0]+ss[1]+ss[2]+ss[3]);
}

extern "C" void kernel_launch(void* const* d_in, const int* in_sizes, int n_in,
                              void* d_out, int out_size, void* d_ws, size_t ws_size,
                              hipStream_t stream){
  (void)in_sizes; (void)n_in; (void)out_size; (void)ws_size;
  const float* x_in  = (const float*)d_in[0];
  const float* x_pas = (const float*)d_in[1];
  const float* ldin  = (const float*)d_in[2];
  const float* w1    = (const float*)d_in[3];
  const float* b1    = (const float*)d_in[4];
  const float* w2    = (const float*)d_in[5];
  const float* b2    = (const float*)d_in[6];
  const float* phase = (const float*)d_in[7];
  float* out   = (float*)d_out;
  float* phi   = out;
  float* ldout = out + (size_t)1024*4096;

  // workspace layout (needs ~118.5 MB)
  char* ws = (char*)d_ws;
  float* stats = (float*)ws;                       // 8 B
  u16* xn   = (u16*)(ws + 256);                    // 8 MB   [1024][4096] bf16
  u16* w1t  = (u16*)(ws + 8388864);                // 4 MB   [512][4096] bf16
  u16* hb   = (u16*)(ws + 12583168);               // 1 MB   [1024][512] bf16
  u16* w2t  = (u16*)(ws + 13631744);               // 96 MB  [98304][512] bf16
  float* part = (float*)(ws + 114295040);          // 4 MB   [1024][1024] f32

  hipMemsetAsync(stats, 0, 8, stream);
  k_stats<<<1024, 256, 0, stream>>>(x_pas, stats);
  k_prep<<<2048, 256, 0, stream>>>(x_pas, stats, xn);
  k_transpose_cvt<<<dim3(64, 8),   256, 0, stream>>>(w1, w1t, 4096, 512);
  k_transpose_cvt<<<dim3(8, 1536), 256, 0, stream>>>(w2, w2t, 512, 98304);
  k_gemm1<<<dim3(8, 16), 256, 0, stream>>>(xn, w1t, b1, hb);
  k_gemm2<<<dim3(1024, 4), 256, 0, stream>>>(hb, w2t, b2, x_in, phase, phi, part);
  k_ldred<<<1024, 256, 0, stream>>>(part, ldin, ldout);
}

// Round 3
// 569.092 us; speedup vs baseline: 1.0668x; 1.0668x over previous
//
#include <hip/hip_runtime.h>
#include <cstdint>
#include <cstddef>

// ---------------------------------------------------------------------------
// CircularSplineLayer pipeline:
//  k_stats          global sum/sumsq of x_passive
//  k_prep           xn -> bf16 [1024][4096]
//  k_transpose_cvt  f32 [K][N] -> bf16 [N][K], 256x128 tiles, XOR-swizzled LDS
//  k_gemm1          split-K=2 MFMA bf16, partials f32
//  k_gemm1b         combine partials + bias + tanh -> h bf16 [1024][512]
//  k_gemm2          MFMA tile 256x96, grid (4,1024) for L2 reuse, fused spline
//  k_ldred          per-b reduction of log-grad partials
// ---------------------------------------------------------------------------

typedef unsigned short u16;
typedef __bf16 bf16x8 __attribute__((ext_vector_type(8)));
typedef float f32x4 __attribute__((ext_vector_type(4)));
typedef unsigned short u16x8 __attribute__((ext_vector_type(8)));
typedef unsigned short u16x4 __attribute__((ext_vector_type(4)));
typedef unsigned short u16x2 __attribute__((ext_vector_type(2)));

#define TWOPI_F 6.28318530717958647692f

static __device__ __forceinline__ u16 f32_to_bf16(float f){
  unsigned u = __builtin_bit_cast(unsigned, f);
  return (u16)((u + 0x7fffu + ((u >> 16) & 1u)) >> 16);   // RNE
}
static __device__ __forceinline__ void async16(void* lds, const void* g){
  // global->LDS DMA, 16B/lane; LDS dest = wave-uniform base + lane*16
  __builtin_amdgcn_global_load_lds((const __attribute__((address_space(1))) void*)g,
                                   (__attribute__((address_space(3))) void*)lds,
                                   16, 0, 0);
}
static __device__ __forceinline__ float fast_tanh(float x){
  x = fminf(fmaxf(x, -15.f), 15.f);
  float e = __expf(2.f * x);
  return (e - 1.f) / (e + 1.f);
}
static __device__ __forceinline__ float softplus_f(float x){
  return fmaxf(x, 0.f) + __logf(1.f + __expf(-fabsf(x)));
}

// ---- global sum / sumsq of x_passive (4194304 f32) ----
__global__ void k_stats(const float* __restrict__ xp, float* __restrict__ stats){
  __shared__ float ss[4], sq[4];
  const int tid = threadIdx.x;
  const long gt = (long)blockIdx.x * 256 + tid;          // float4 index
  const float4* x4 = (const float4*)xp;
  float s = 0.f, q = 0.f;
  #pragma unroll
  for (int p = 0; p < 4; ++p){
    float4 v = x4[gt + (long)p * 262144];
    s += v.x + v.y + v.z + v.w;
    q += v.x*v.x + v.y*v.y + v.z*v.z + v.w*v.w;
  }
  #pragma unroll
  for (int off = 32; off; off >>= 1){
    s += __shfl_down(s, off);
    q += __shfl_down(q, off);
  }
  if ((tid & 63) == 0){ ss[tid>>6] = s; sq[tid>>6] = q; }
  __syncthreads();
  if (tid == 0){
    atomicAdd(stats,     ss[0]+ss[1]+ss[2]+ss[3]);
    atomicAdd(stats + 1, sq[0]+sq[1]+sq[2]+sq[3]);
  }
}

// ---- xn = (x - mean)*istd -> bf16 ----
__global__ void k_prep(const float* __restrict__ xp, const float* __restrict__ stats,
                       u16* __restrict__ xn){
  const long t = (long)blockIdx.x * 256 + threadIdx.x;   // 524288 threads, 8 elems each
  const float sum = stats[0], sq = stats[1];
  const float N = 4194304.f;
  const float mean = sum / N;
  const float istd = rsqrtf((sq - sum*sum/N) / (N - 1.f));  // ddof=1
  const float4* x4 = (const float4*)xp;
  const float4 a = x4[2*t], b = x4[2*t+1];
  u16x8 o;
  o[0]=f32_to_bf16((a.x-mean)*istd); o[1]=f32_to_bf16((a.y-mean)*istd);
  o[2]=f32_to_bf16((a.z-mean)*istd); o[3]=f32_to_bf16((a.w-mean)*istd);
  o[4]=f32_to_bf16((b.x-mean)*istd); o[5]=f32_to_bf16((b.y-mean)*istd);
  o[6]=f32_to_bf16((b.z-mean)*istd); o[7]=f32_to_bf16((b.w-mean)*istd);
  ((u16x8*)xn)[t] = o;
}

// ---- f32 [Kd][Nd] -> bf16 [Nd][Kd]; 256(k) x 128(n) tiles ----
// Store: k-pair P of row n lands at pair-position P ^ (sigma<<2), sigma=(n>>2)&7
// (an XOR on the pair-GROUP index P>>2). Read: pair-group lk is therefore at
// group-position lk ^ sigma. Global reads AND writes stay 512B-contiguous.
__global__ __launch_bounds__(256) void k_transpose_cvt(const float* __restrict__ in,
                                                       u16* __restrict__ out,
                                                       int Kd, int Nd){
  __shared__ __align__(16) u16 tT[128*256];
  const int tid = threadIdx.x;
  const long k0 = (long)blockIdx.x * 256, n0 = (long)blockIdx.y * 128;
  const int lam = tid & 31, g = tid >> 5;
  const int c = lam * 4;
  const int sig = (lam & 7) << 2;                 // (sigma)<<2, sigma=(n>>2)&7
  #pragma unroll
  for (int pass = 0; pass < 16; ++pass){
    const int P = pass*8 + g;                     // k-pair index 0..127
    const float4 f0 = *(const float4*)&in[(k0 + 2*P    )*Nd + n0 + c];
    const float4 f1 = *(const float4*)&in[(k0 + 2*P + 1)*Nd + n0 + c];
    const int pp = 2*(P ^ sig);
    *(u16x2*)&tT[(c    )*256 + pp] = u16x2{f32_to_bf16(f0.x), f32_to_bf16(f1.x)};
    *(u16x2*)&tT[(c + 1)*256 + pp] = u16x2{f32_to_bf16(f0.y), f32_to_bf16(f1.y)};
    *(u16x2*)&tT[(c + 2)*256 + pp] = u16x2{f32_to_bf16(f0.z), f32_to_bf16(f1.z)};
    *(u16x2*)&tT[(c + 3)*256 + pp] = u16x2{f32_to_bf16(f0.w), f32_to_bf16(f1.w)};
  }
  __syncthreads();
  const int w = tid >> 6, l = tid & 63;
  const int lh = l >> 5, lk = l & 31;
  #pragma unroll
  for (int it = 0; it < 16; ++it){
    const int n = (w << 5) + (it << 1) + lh;
    const int s2 = (n >> 2) & 7;                  // sigma (group-index XOR) — NOT <<2
    const u16x8 v = *(const u16x8*)&tT[n*256 + 8*(lk ^ s2)];
    *(u16x8*)&out[(n0 + n)*Kd + k0 + 8*lk] = v;
  }
}

// ---- GEMM1 split-K: partial = xn @ w1 over half of K. M=1024 N=512 ----
__global__ __launch_bounds__(256, 2) void k_gemm1(
    const u16* __restrict__ xn,   // [1024][4096] bf16
    const u16* __restrict__ w1t,  // [512][4096] bf16 (n-major)
    float* __restrict__ pp)       // [2][1024][512] f32 partials
{
  __shared__ __align__(16) u16 sA[64*32];
  __shared__ __align__(16) u16 sB[64*32];
  const int tid = threadIdx.x, lane = tid & 63, w = tid >> 6;
  const int n0 = blockIdx.x << 6, m0 = blockIdx.y << 6;
  const int ks = blockIdx.z;
  const int wm = w >> 1, wn = w & 1;
  const int rA = lane >> 2, cA = (lane & 3) << 3;
  const int fr = lane & 15, fq = lane >> 4;
  const f32x4 z4 = {0.f, 0.f, 0.f, 0.f};
  f32x4 acc[2][2];
  #pragma unroll
  for (int i=0;i<2;i++){ acc[i][0] = z4; acc[i][1] = z4; }

  for (int kt = 0; kt < 64; ++kt){
    const int kofs = (ks << 11) + (kt << 5) + cA;
    async16(sA + w*512, xn  + (long)(m0 + w*16 + rA)*4096 + kofs);
    async16(sB + w*512, w1t + (long)(n0 + w*16 + rA)*4096 + kofs);
    __syncthreads();
    bf16x8 af[2], bfv[2];
    #pragma unroll
    for (int i=0;i<2;i++) af[i]  = *(const bf16x8*)(sA + ((wm<<5) + i*16 + fr)*32 + (fq<<3));
    #pragma unroll
    for (int j=0;j<2;j++) bfv[j] = *(const bf16x8*)(sB + ((wn<<5) + j*16 + fr)*32 + (fq<<3));
    #pragma unroll
    for (int i=0;i<2;i++)
      #pragma unroll
      for (int j=0;j<2;j++)
        acc[i][j] = __builtin_amdgcn_mfma_f32_16x16x32_bf16(af[i], bfv[j], acc[i][j], 0, 0, 0);
    __syncthreads();
  }
  float* po = pp + ((size_t)ks << 19);
  #pragma unroll
  for (int i=0;i<2;i++)
    #pragma unroll
    for (int j=0;j<2;j++)
      #pragma unroll
      for (int r=0;r<4;r++){
        const int row = m0 + (wm<<5) + i*16 + (fq<<2) + r;   // C/D: row=(lane>>4)*4+reg
        const int col = n0 + (wn<<5) + j*16 + fr;            //      col=lane&15
        po[row*512 + col] = acc[i][j][r];
      }
}

// ---- combine split-K partials: h = tanh(p0+p1+b1) -> bf16 ----
__global__ void k_gemm1b(const float* __restrict__ pp, const float* __restrict__ b1,
                         u16* __restrict__ hb){
  const int t = blockIdx.x * 256 + threadIdx.x;    // 131072 float4 groups
  const float4 a = ((const float4*)pp)[t];
  const float4 b = ((const float4*)pp)[131072 + t];
  const float4 bb = ((const float4*)b1)[t & 127];
  u16x4 o;
  o[0] = f32_to_bf16(fast_tanh(a.x + b.x + bb.x));
  o[1] = f32_to_bf16(fast_tanh(a.y + b.y + bb.y));
  o[2] = f32_to_bf16(fast_tanh(a.z + b.z + bb.z));
  o[3] = f32_to_bf16(fast_tanh(a.w + b.w + bb.w));
  ((u16x4*)hb)[t] = o;
}

// ---- GEMM2 + spline epilogue: M=1024 N=98304 K=512, tile 256x96 ----
// grid (4,1024): the 4 m-tiles of one nt are dispatch-adjacent -> w2t strip
// (96KB) and hmat stay L2-resident across them.
__global__ __launch_bounds__(256, 2) void k_gemm2(
    const u16* __restrict__ hmat,   // [1024][512] bf16
    const u16* __restrict__ w2t,    // [98304][512] bf16 (n-major)
    const float* __restrict__ b2,
    const float* __restrict__ x_in, // [1024][4096]
    const float* __restrict__ phase,
    float* __restrict__ phi_out,    // [1024][4096]
    float* __restrict__ part)       // [1024][1024] log-grad partials (b, ntile)
{
  __shared__ __align__(16) char smem[25600];
  u16* sA = (u16*)smem;              // [256][32] bf16 staging
  u16* sB = (u16*)(smem + 16384);    // [128][32] bf16 (rows >=96 are pad)
  float* sC = (float*)smem;          // [4 waves][16 rows][100] epilogue (reuses smem)

  const int tid  = threadIdx.x;
  const int lane = tid & 63;
  const int w    = tid >> 6;
  const int nt   = blockIdx.y;           // 0..1023
  const int m0   = blockIdx.x << 8;      // 0,256,512,768
  const long n0  = (long)nt * 96;

  const int rA = lane >> 2, cA = (lane & 3) << 3;
  const int fr = lane & 15, fq = lane >> 4;

  const f32x4 z4 = {0.f, 0.f, 0.f, 0.f};
  f32x4 acc[4][6];
  #pragma unroll
  for (int i=0;i<4;i++)
    #pragma unroll
    for (int j=0;j<6;j++) acc[i][j] = z4;

  for (int kt = 0; kt < 16; ++kt){
    const int kofs = (kt << 5) + cA;
    #pragma unroll
    for (int cc = 0; cc < 4; ++cc){
      const int c = (w << 2) + cc;                         // 16 A chunks of 16 rows
      async16(sA + c*512, hmat + (long)(m0 + c*16 + rA)*512 + kofs);
    }
    #pragma unroll
    for (int cc = 0; cc < 2; ++cc){
      const int ch = (w << 1) + cc;                        // 8 B chunks (2 pad)
      int row = ch*16 + rA; if (row > 95) row = 95;        // clamp into valid rows
      async16(sB + ch*512, w2t + (n0 + row)*512 + kofs);
    }
    __syncthreads();                                       // drains vmcnt for DMA
    bf16x8 af[4], bfv[6];
    #pragma unroll
    for (int i=0;i<4;i++)
      af[i] = *(const bf16x8*)(sA + ((w<<6) + i*16 + fr)*32 + (fq<<3));
    #pragma unroll
    for (int j=0;j<6;j++)
      bfv[j] = *(const bf16x8*)(sB + (j*16 + fr)*32 + (fq<<3));
    #pragma unroll
    for (int i=0;i<4;i++)
      #pragma unroll
      for (int j=0;j<6;j++)
        acc[i][j] = __builtin_amdgcn_mfma_f32_16x16x32_bf16(af[i], bfv[j], acc[i][j], 0, 0, 0);
    __syncthreads();
  }

  // ---- epilogue: tanh+bias -> LDS -> per-(b,s_out) spline ----
  const float shift = phase[0];
  float b2c[6];
  #pragma unroll
  for (int j=0;j<6;j++) b2c[j] = b2[n0 + j*16 + fr];
  float* myC = sC + w*1600;                                // 16 rows x 100 floats

  #pragma unroll
  for (int q = 0; q < 4; ++q){                             // quarter = row-frag index
    __syncthreads();
    #pragma unroll
    for (int j=0;j<6;j++)
      #pragma unroll
      for (int r=0;r<4;r++)
        myC[((fq<<2)+r)*100 + j*16 + fr] = fast_tanh(acc[q][j][r] + b2c[j]);
    __syncthreads();

    const int row = fr;                 // 0..15 within quarter
    const int g   = fq;                 // s_out group 0..3
    const float* tp = myC + row*100 + g*24;
    float t[24];
    #pragma unroll
    for (int jj=0;jj<24;jj++) t[jj] = tp[jj];

    const int bg = m0 + (w<<6) + (q<<4) + row;
    const int s  = (nt<<2) + g;
    const float x = x_in[(long)bg*4096 + s];

    // softmax over h_raw (t[0..7]) and w_raw (t[8..15]); tanh out in (-1,1) so no max-shift needed
    float eh[8], ew[8];
    float sh = 0.f, sw = 0.f;
    #pragma unroll
    for (int i=0;i<8;i++){ eh[i] = __expf(t[i]);   sh += eh[i]; }
    #pragma unroll
    for (int i=0;i<8;i++){ ew[i] = __expf(t[8+i]); sw += ew[i]; }
    const float fh = TWOPI_F / sh, fw = TWOPI_F / sw;

    // bin index: #{cumsum_w_i < x, i=1..8}, clipped to 7
    float cw = 0.f; int k = 0;
    #pragma unroll
    for (int i=0;i<8;i++){ cw += ew[i]*fw; k += (cw < x) ? 1 : 0; }
    if (k > 7) k = 7;

    float xkm1 = -1e-6f, ph = 0.f, wk = 0.f, hk = 0.f, dr0 = 0.f, dr1 = 0.f;
    float cw2 = 0.f, chs = 0.f;
    #pragma unroll
    for (int i=0;i<8;i++){
      const float wi = ew[i]*fw, hi = eh[i]*fh;
      if (i == k){
        wk = wi; hk = hi;
        xkm1 = (i == 0) ? -1e-6f : cw2;   // x_kp[k]
        ph = chs;                         // phi_kp[k]
        dr0 = t[16 + i];
        dr1 = t[16 + ((i+1)&7)];
      }
      cw2 += wi; chs += hi;
    }
    const float dk  = softplus_f(dr0);
    const float dk1 = softplus_f(dr1);
    const float sk  = hk / wk;
    const float alpha = (x - xkm1) / wk;
    const float a1m = alpha * (1.f - alpha);
    const float denom = sk + (dk1 + dk - 2.f*sk)*a1m;
    const float phiv = ph + hk*(sk*alpha*alpha + dk*a1m)/denom;
    float p = phiv + shift;                 // in [0, 2pi+1): conditional subtract == mod
    if (p >= TWOPI_F) p -= TWOPI_F;
    if (p >= TWOPI_F) p -= TWOPI_F;
    phi_out[(long)bg*4096 + s] = p;

    const float om = 1.f - alpha;
    const float num = dk1*alpha*alpha + 2.f*sk*a1m + dk*om*om;
    float lg = __logf(sk*sk*num/(denom*denom));
    lg += __shfl_xor(lg, 16);               // sum over the 4 s_out groups (same row)
    lg += __shfl_xor(lg, 32);
    if (lane < 16) part[(long)bg*1024 + nt] = lg;
  }
}

// ---- log_density[b] = ldin[b] - sum_nt part[b][nt] ----
__global__ void k_ldred(const float* __restrict__ part, const float* __restrict__ ldin,
                        float* __restrict__ ldout){
  __shared__ float ss[4];
  const int b = blockIdx.x, tid = threadIdx.x;
  const float4* p4 = (const float4*)(part + ((long)b << 10));
  const float4 v = p4[tid];
  float s = v.x + v.y + v.z + v.w;
  #pragma unroll
  for (int off = 32; off; off >>= 1) s += __shfl_down(s, off);
  if ((tid & 63) == 0) ss[tid >> 6] = s;
  __syncthreads();
  if (tid == 0) ldout[b] = ldin[b] - (ss[0]+ss[1]+ss[2]+ss[3]);
}

extern "C" void kernel_launch(void* const* d_in, const int* in_sizes, int n_in,
                              void* d_out, int out_size, void* d_ws, size_t ws_size,
                              hipStream_t stream){
  (void)in_sizes; (void)n_in; (void)out_size; (void)ws_size;
  const float* x_in  = (const float*)d_in[0];
  const float* x_pas = (const float*)d_in[1];
  const float* ldin  = (const float*)d_in[2];
  const float* w1    = (const float*)d_in[3];
  const float* b1    = (const float*)d_in[4];
  const float* w2    = (const float*)d_in[5];
  const float* b2    = (const float*)d_in[6];
  const float* phase = (const float*)d_in[7];
  float* out   = (float*)d_out;
  float* phi   = out;
  float* ldout = out + (size_t)1024*4096;

  // workspace layout (needs ~118.5 MB)
  char* ws = (char*)d_ws;
  float* stats = (float*)ws;                       // 8 B
  u16* xn   = (u16*)(ws + 256);                    // 8 MB   [1024][4096] bf16
  u16* w1t  = (u16*)(ws + 8388864);                // 4 MB   [512][4096] bf16
  u16* hb   = (u16*)(ws + 12583168);               // 1 MB   [1024][512] bf16
  u16* w2t  = (u16*)(ws + 13631744);               // 96 MB  [98304][512] bf16
  float* part = (float*)(ws + 114295040);          // 4 MB   gemm1 partials, then [1024][1024] log-grad

  hipMemsetAsync(stats, 0, 8, stream);
  k_stats<<<1024, 256, 0, stream>>>(x_pas, stats);
  k_prep<<<2048, 256, 0, stream>>>(x_pas, stats, xn);
  k_transpose_cvt<<<dim3(16, 4),  256, 0, stream>>>(w1, w1t, 4096, 512);
  k_transpose_cvt<<<dim3(2, 768), 256, 0, stream>>>(w2, w2t, 512, 98304);
  k_gemm1<<<dim3(8, 16, 2), 256, 0, stream>>>(xn, w1t, part);
  k_gemm1b<<<512, 256, 0, stream>>>(part, b1, hb);
  k_gemm2<<<dim3(4, 1024), 256, 0, stream>>>(hb, w2t, b2, x_in, phase, phi, part);
  k_ldred<<<1024, 256, 0, stream>>>(part, ldin, ldout);
}